// Round 1
// baseline (289.709 us; speedup 1.0000x reference)
//
#include <hip/hip_runtime.h>
#include <cmath>

#define HE 361
#define WE 720
#define LL 37
#define HM 180
#define WM 360
#define KK 32
#define EPSF 1e-8f

// out layout: out3d [HM*WM*KK*5] | p_model [HM*WM*KK] | ps_o [HM*WM]
#define OFF1 ((size_t)HM * WM * KK * 5)
#define OFF2 (OFF1 + (size_t)HM * WM * KK)

// ws layout (4B units):
// [0,180)    iy   (int)
// [180,360)  ty   (float)
// [360,720)  ix   (int)
// [720,1080) tx   (float)
// [1080,1117) logpe (float)

__device__ __forceinline__ int upper_bound_g(const float* a, int n, float v) {
    int lo = 0, hi = n;
    while (lo < hi) {
        int m = (lo + hi) >> 1;
        if (a[m] <= v) lo = m + 1; else hi = m;
    }
    return lo;  // first index with a[i] > v  (== searchsorted side='right')
}

__global__ void precompute_kernel(const float* __restrict__ era5_lat,
                                  const float* __restrict__ era5_lon,
                                  const float* __restrict__ model_lat,
                                  const float* __restrict__ model_lon,
                                  const float* __restrict__ p_levels,
                                  int* __restrict__ ws_iy, float* __restrict__ ws_ty,
                                  int* __restrict__ ws_ix, float* __restrict__ ws_tx,
                                  float* __restrict__ ws_logpe) {
    int t = blockIdx.x * blockDim.x + threadIdx.x;
    if (t < HM) {
        float v = model_lat[t];
        int i = upper_bound_g(era5_lat, HE, v) - 1;
        if (i < 0) i = 0;
        if (i > HE - 2) i = HE - 2;
        ws_iy[t] = i;
        ws_ty[t] = (v - era5_lat[i]) / (era5_lat[i + 1] - era5_lat[i]);
    } else if (t < HM + WM) {
        int j = t - HM;
        float v = model_lon[j];
        int i = upper_bound_g(era5_lon, WE, v) - 1;
        if (i < 0) i = 0;
        if (i > WE - 2) i = WE - 2;
        ws_ix[j] = i;
        ws_tx[j] = (v - era5_lon[i]) / (era5_lon[i + 1] - era5_lon[i]);
    } else if (t < HM + WM + LL) {
        int k = t - HM - WM;
        ws_logpe[k] = logf(p_levels[k] + EPSF);
    }
}

__global__ void __launch_bounds__(256)
main_kernel(const float* __restrict__ u, const float* __restrict__ v,
            const float* __restrict__ w, const float* __restrict__ T,
            const float* __restrict__ q, const float* __restrict__ ps,
            const float* __restrict__ p_levels,
            const float* __restrict__ a_k, const float* __restrict__ b_k,
            const int* __restrict__ ws_iy, const float* __restrict__ ws_ty,
            const int* __restrict__ ws_ix, const float* __restrict__ ws_tx,
            const float* __restrict__ ws_logpe,
            float* __restrict__ out) {
    __shared__ float s_plev[LL];
    __shared__ float s_logpe[LL];
    __shared__ float s_ak[KK];
    __shared__ float s_bk[KK];
    __shared__ float hdbuf[LL * 256];

    const int tid = threadIdx.x;
    if (tid < LL) {
        s_plev[tid]  = p_levels[tid];
        s_logpe[tid] = ws_logpe[tid];
    }
    if (tid < KK) {
        s_ak[tid] = a_k[tid];
        s_bk[tid] = b_k[tid];
    }
    __syncthreads();

    const int id = blockIdx.x * blockDim.x + tid;
    if (id >= HM * WM) return;

    const int y = id / WM;
    const int x = id - y * WM;

    const int   iy = ws_iy[y];
    const float ty = ws_ty[y];
    const int   ix = ws_ix[x];
    const float tx = ws_tx[x];

    const size_t b00 = (size_t)iy * WE + ix;
    const size_t b01 = b00 + 1;
    const size_t b10 = b00 + WE;
    const size_t b11 = b10 + 1;

    const float omty = 1.0f - ty;
    const float omtx = 1.0f - tx;

    // surface pressure bilinear
    const float p00 = ps[b00], p01 = ps[b01], p10 = ps[b10], p11 = ps[b11];
    const float ps_m = omty * (omtx * p00 + tx * p01) + ty * (omtx * p10 + tx * p11);

    // nvalid = # p_levels <= ps_m
    int nvalid = 0;
#pragma unroll
    for (int l = 0; l < LL; l++) nvalid += (s_plev[l] <= ps_m) ? 1 : 0;

    // ps_o
    out[OFF2 + id] = fminf(fmaxf(ps_m, 30000.0f), 110000.0f);

    int maxi = nvalid - 2;
    if (maxi < 0) maxi = 0;

    float t_arr[KK];
    int   idx_arr[KK];
#pragma unroll
    for (int k = 0; k < KK; k++) {
        const float pm = s_ak[k] + s_bk[k] * ps_m;
        out[OFF1 + (size_t)id * KK + k] = pm;
        const float lpm = logf(pm + EPSF);
        // upper_bound over s_logpe (37)
        int lo = 0, hi = LL;
        while (lo < hi) {
            int m = (lo + hi) >> 1;
            if (s_logpe[m] <= lpm) lo = m + 1; else hi = m;
        }
        int i = lo - 1;
        if (i < 0) i = 0;
        if (i > maxi) i = maxi;
        const float x0 = s_logpe[i];
        const float x1 = s_logpe[i + 1];
        t_arr[k] = (lpm - x0) / (x1 - x0);
        idx_arr[k] = i;
    }

    const float* srcs[5] = {u, v, w, T, q};
#pragma unroll
    for (int v5 = 0; v5 < 5; v5++) {
        const float* s   = srcs[v5];
        const float* a00 = s + b00 * LL;
        const float* a01 = s + b01 * LL;
        const float* a10 = s + b10 * LL;
        const float* a11 = s + b11 * LL;
        for (int l = 0; l < LL; l++) {
            const float hv = omty * (omtx * a00[l] + tx * a01[l]) +
                             ty   * (omtx * a10[l] + tx * a11[l]);
            hdbuf[l * 256 + tid] = hv;
        }
        // no __syncthreads needed: each thread only touches its own column
#pragma unroll
        for (int k = 0; k < KK; k++) {
            const int i = idx_arr[k];
            const float g0 = hdbuf[i * 256 + tid];
            const float g1 = hdbuf[(i + 1) * 256 + tid];
            float o = g0 + t_arr[k] * (g1 - g0);
            if (nvalid < 2) o = 0.0f;               // zero BEFORE clip (matches ref)
            if (v5 == 3) o = fminf(fmaxf(o, 150.0f), 350.0f);
            if (v5 == 4) o = fminf(fmaxf(o, 0.0f), 0.05f);
            out[(size_t)id * (KK * 5) + k * 5 + v5] = o;
        }
    }
}

extern "C" void kernel_launch(void* const* d_in, const int* in_sizes, int n_in,
                              void* d_out, int out_size, void* d_ws, size_t ws_size,
                              hipStream_t stream) {
    const float* u         = (const float*)d_in[0];
    const float* v         = (const float*)d_in[1];
    const float* w         = (const float*)d_in[2];
    const float* T         = (const float*)d_in[3];
    const float* q         = (const float*)d_in[4];
    const float* ps        = (const float*)d_in[5];
    const float* era5_lat  = (const float*)d_in[6];
    const float* era5_lon  = (const float*)d_in[7];
    const float* model_lat = (const float*)d_in[8];
    const float* model_lon = (const float*)d_in[9];
    const float* p_levels  = (const float*)d_in[10];
    const float* a_k       = (const float*)d_in[11];
    const float* b_k       = (const float*)d_in[12];

    int*   ws_iy    = (int*)d_ws;
    float* ws_ty    = (float*)d_ws + 180;
    int*   ws_ix    = (int*)d_ws + 360;
    float* ws_tx    = (float*)d_ws + 720;
    float* ws_logpe = (float*)d_ws + 1080;

    float* out = (float*)d_out;

    precompute_kernel<<<3, 256, 0, stream>>>(era5_lat, era5_lon, model_lat, model_lon,
                                             p_levels, ws_iy, ws_ty, ws_ix, ws_tx,
                                             ws_logpe);

    const int npts = HM * WM;
    const int blocks = (npts + 255) / 256;
    main_kernel<<<blocks, 256, 0, stream>>>(u, v, w, T, q, ps, p_levels, a_k, b_k,
                                            ws_iy, ws_ty, ws_ix, ws_tx, ws_logpe, out);
}

// Round 2
// 258.590 us; speedup vs baseline: 1.1203x; 1.1203x over previous
//
#include <hip/hip_runtime.h>
#include <cmath>

#define HE 361
#define WE 720
#define LL 37
#define HM 180
#define WM 360
#define KK 32
#define NPTS (HM * WM)
#define EPSF 1e-8f

// out layout: out3d [HM*WM*KK*5] | p_model [HM*WM*KK] | ps_o [HM*WM]
#define OFF1 ((size_t)HM * WM * KK * 5)
#define OFF2 (OFF1 + (size_t)HM * WM * KK)

// ws layout (float units):
#define WS_IY    0
#define WS_TY    180
#define WS_IX    360
#define WS_TX    720
#define WS_LOGPE 1080
#define WS_PSM   1120
#define WS_VARSH (1120 + NPTS)
#define WS_NEEDED_FLOATS ((size_t)WS_VARSH + (size_t)NPTS * 5 * LL)

__device__ __forceinline__ int upper_bound_g(const float* a, int n, float v) {
    int lo = 0, hi = n;
    while (lo < hi) {
        int m = (lo + hi) >> 1;
        if (a[m] <= v) lo = m + 1; else hi = m;
    }
    return lo;  // searchsorted side='right'
}

__global__ void precompute_kernel(const float* __restrict__ era5_lat,
                                  const float* __restrict__ era5_lon,
                                  const float* __restrict__ model_lat,
                                  const float* __restrict__ model_lon,
                                  const float* __restrict__ p_levels,
                                  int* __restrict__ ws_iy, float* __restrict__ ws_ty,
                                  int* __restrict__ ws_ix, float* __restrict__ ws_tx,
                                  float* __restrict__ ws_logpe) {
    int t = blockIdx.x * blockDim.x + threadIdx.x;
    if (t < HM) {
        float v = model_lat[t];
        int i = upper_bound_g(era5_lat, HE, v) - 1;
        if (i < 0) i = 0;
        if (i > HE - 2) i = HE - 2;
        ws_iy[t] = i;
        ws_ty[t] = (v - era5_lat[i]) / (era5_lat[i + 1] - era5_lat[i]);
    } else if (t < HM + WM) {
        int j = t - HM;
        float v = model_lon[j];
        int i = upper_bound_g(era5_lon, WE, v) - 1;
        if (i < 0) i = 0;
        if (i > WE - 2) i = WE - 2;
        ws_ix[j] = i;
        ws_tx[j] = (v - era5_lon[i]) / (era5_lon[i + 1] - era5_lon[i]);
    } else if (t < HM + WM + LL) {
        int k = t - HM - WM;
        ws_logpe[k] = logf(p_levels[k] + EPSF);
    }
}

// ps bilinear: one thread per model point. writes ps_m (ws) and ps_o (out).
__global__ void __launch_bounds__(256)
ps_kernel(const float* __restrict__ ps,
          const int* __restrict__ ws_iy, const float* __restrict__ ws_ty,
          const int* __restrict__ ws_ix, const float* __restrict__ ws_tx,
          float* __restrict__ ws_psm, float* __restrict__ out) {
    const int id = blockIdx.x * blockDim.x + threadIdx.x;
    if (id >= NPTS) return;
    const int y = id / WM;
    const int x = id - y * WM;
    const int   iy = ws_iy[y];
    const float ty = ws_ty[y];
    const int   ix = ws_ix[x];
    const float tx = ws_tx[x];
    const size_t b00 = (size_t)iy * WE + ix;
    const float p00 = ps[b00], p01 = ps[b00 + 1];
    const float p10 = ps[b00 + WE], p11 = ps[b00 + WE + 1];
    const float ps_m = (1.0f - ty) * ((1.0f - tx) * p00 + tx * p01) +
                       ty * ((1.0f - tx) * p10 + tx * p11);
    ws_psm[id] = ps_m;
    out[OFF2 + id] = fminf(fmaxf(ps_m, 30000.0f), 110000.0f);
}

// horizontal bilinear: one thread per (pt, var, level). 12M threads.
// vars_h[pt*185 + var*37 + l]
__global__ void __launch_bounds__(256)
horiz_kernel(const float* __restrict__ u, const float* __restrict__ v,
             const float* __restrict__ w, const float* __restrict__ T,
             const float* __restrict__ q,
             const int* __restrict__ ws_iy, const float* __restrict__ ws_ty,
             const int* __restrict__ ws_ix, const float* __restrict__ ws_tx,
             float* __restrict__ vars_h) {
    const int g = blockIdx.x * blockDim.x + threadIdx.x;
    const int TOT = NPTS * 5 * LL;
    if (g >= TOT) return;
    const int pt  = g / (5 * LL);
    const int rem = g - pt * (5 * LL);
    const int var = rem / LL;
    const int l   = rem - var * LL;

    const int y = pt / WM;
    const int x = pt - y * WM;
    const int   iy = ws_iy[y];
    const float ty = ws_ty[y];
    const int   ix = ws_ix[x];
    const float tx = ws_tx[x];

    const float* s = (var == 0) ? u : (var == 1) ? v : (var == 2) ? w
                   : (var == 3) ? T : q;

    const size_t c00 = ((size_t)iy * WE + ix) * LL + l;
    const float d00 = s[c00];
    const float d01 = s[c00 + LL];
    const float d10 = s[c00 + (size_t)WE * LL];
    const float d11 = s[c00 + (size_t)WE * LL + LL];

    const float hv = (1.0f - ty) * ((1.0f - tx) * d00 + tx * d01) +
                     ty * ((1.0f - tx) * d10 + tx * d11);
    vars_h[g] = hv;
}

// vertical interp: one thread per (pt, k). 2.07M threads.
__global__ void __launch_bounds__(256)
vert_kernel(const float* __restrict__ vars_h, const float* __restrict__ ws_psm,
            const float* __restrict__ p_levels, const float* __restrict__ ws_logpe,
            const float* __restrict__ a_k, const float* __restrict__ b_k,
            float* __restrict__ out) {
    __shared__ float s_plev[LL];
    __shared__ float s_logpe[LL];
    __shared__ float s_ak[KK];
    __shared__ float s_bk[KK];
    const int tid = threadIdx.x;
    if (tid < LL) {
        s_plev[tid]  = p_levels[tid];
        s_logpe[tid] = ws_logpe[tid];
    }
    if (tid < KK) {
        s_ak[tid] = a_k[tid];
        s_bk[tid] = b_k[tid];
    }
    __syncthreads();

    const int g = blockIdx.x * blockDim.x + tid;
    if (g >= NPTS * KK) return;
    const int pt = g / KK;
    const int k  = g - pt * KK;

    const float ps_m = ws_psm[pt];

    int nvalid = 0;
#pragma unroll
    for (int l = 0; l < LL; l++) nvalid += (s_plev[l] <= ps_m) ? 1 : 0;
    int maxi = nvalid - 2;
    if (maxi < 0) maxi = 0;

    const float pm = s_ak[k] + s_bk[k] * ps_m;
    out[OFF1 + (size_t)g] = pm;   // p_model, layout [pt][k] == g

    const float lpm = logf(pm + EPSF);
    int lo = 0, hi = LL;
    while (lo < hi) {
        int m = (lo + hi) >> 1;
        if (s_logpe[m] <= lpm) lo = m + 1; else hi = m;
    }
    int i = lo - 1;
    if (i < 0) i = 0;
    if (i > maxi) i = maxi;
    const float x0 = s_logpe[i];
    const float x1 = s_logpe[i + 1];
    const float t = (lpm - x0) / (x1 - x0);

    const float* col = vars_h + (size_t)pt * (5 * LL);
    const bool invalid = (nvalid < 2);
#pragma unroll
    for (int var = 0; var < 5; var++) {
        const float g0 = col[var * LL + i];
        const float g1 = col[var * LL + i + 1];
        float o = g0 + t * (g1 - g0);
        if (invalid) o = 0.0f;                       // zero, THEN clip (matches ref)
        if (var == 3) o = fminf(fmaxf(o, 150.0f), 350.0f);
        if (var == 4) o = fminf(fmaxf(o, 0.0f), 0.05f);
        out[(size_t)pt * (KK * 5) + k * 5 + var] = o;
    }
}

// ---------------- fallback (round-1 proven single kernel) ----------------
__global__ void __launch_bounds__(256)
main_kernel(const float* __restrict__ u, const float* __restrict__ v,
            const float* __restrict__ w, const float* __restrict__ T,
            const float* __restrict__ q, const float* __restrict__ ps,
            const float* __restrict__ p_levels,
            const float* __restrict__ a_k, const float* __restrict__ b_k,
            const int* __restrict__ ws_iy, const float* __restrict__ ws_ty,
            const int* __restrict__ ws_ix, const float* __restrict__ ws_tx,
            const float* __restrict__ ws_logpe,
            float* __restrict__ out) {
    __shared__ float s_plev[LL];
    __shared__ float s_logpe[LL];
    __shared__ float s_ak[KK];
    __shared__ float s_bk[KK];
    __shared__ float hdbuf[LL * 256];

    const int tid = threadIdx.x;
    if (tid < LL) { s_plev[tid] = p_levels[tid]; s_logpe[tid] = ws_logpe[tid]; }
    if (tid < KK) { s_ak[tid] = a_k[tid]; s_bk[tid] = b_k[tid]; }
    __syncthreads();

    const int id = blockIdx.x * blockDim.x + tid;
    if (id >= NPTS) return;
    const int y = id / WM;
    const int x = id - y * WM;
    const int   iy = ws_iy[y];
    const float ty = ws_ty[y];
    const int   ix = ws_ix[x];
    const float tx = ws_tx[x];
    const size_t b00 = (size_t)iy * WE + ix;
    const size_t b01 = b00 + 1;
    const size_t b10 = b00 + WE;
    const size_t b11 = b10 + 1;
    const float omty = 1.0f - ty, omtx = 1.0f - tx;
    const float p00 = ps[b00], p01 = ps[b01], p10 = ps[b10], p11 = ps[b11];
    const float ps_m = omty * (omtx * p00 + tx * p01) + ty * (omtx * p10 + tx * p11);
    int nvalid = 0;
#pragma unroll
    for (int l = 0; l < LL; l++) nvalid += (s_plev[l] <= ps_m) ? 1 : 0;
    out[OFF2 + id] = fminf(fmaxf(ps_m, 30000.0f), 110000.0f);
    int maxi = nvalid - 2; if (maxi < 0) maxi = 0;
    float t_arr[KK]; int idx_arr[KK];
#pragma unroll
    for (int k = 0; k < KK; k++) {
        const float pm = s_ak[k] + s_bk[k] * ps_m;
        out[OFF1 + (size_t)id * KK + k] = pm;
        const float lpm = logf(pm + EPSF);
        int lo = 0, hi = LL;
        while (lo < hi) { int m = (lo + hi) >> 1; if (s_logpe[m] <= lpm) lo = m + 1; else hi = m; }
        int i = lo - 1; if (i < 0) i = 0; if (i > maxi) i = maxi;
        t_arr[k] = (lpm - s_logpe[i]) / (s_logpe[i + 1] - s_logpe[i]);
        idx_arr[k] = i;
    }
    const float* srcs[5] = {u, v, w, T, q};
#pragma unroll
    for (int v5 = 0; v5 < 5; v5++) {
        const float* s   = srcs[v5];
        const float* a00 = s + b00 * LL;
        const float* a01 = s + b01 * LL;
        const float* a10 = s + b10 * LL;
        const float* a11 = s + b11 * LL;
        for (int l = 0; l < LL; l++) {
            hdbuf[l * 256 + tid] = omty * (omtx * a00[l] + tx * a01[l]) +
                                   ty   * (omtx * a10[l] + tx * a11[l]);
        }
#pragma unroll
        for (int k = 0; k < KK; k++) {
            const int i = idx_arr[k];
            const float g0 = hdbuf[i * 256 + tid];
            const float g1 = hdbuf[(i + 1) * 256 + tid];
            float o = g0 + t_arr[k] * (g1 - g0);
            if (nvalid < 2) o = 0.0f;
            if (v5 == 3) o = fminf(fmaxf(o, 150.0f), 350.0f);
            if (v5 == 4) o = fminf(fmaxf(o, 0.0f), 0.05f);
            out[(size_t)id * (KK * 5) + k * 5 + v5] = o;
        }
    }
}

extern "C" void kernel_launch(void* const* d_in, const int* in_sizes, int n_in,
                              void* d_out, int out_size, void* d_ws, size_t ws_size,
                              hipStream_t stream) {
    const float* u         = (const float*)d_in[0];
    const float* v         = (const float*)d_in[1];
    const float* w         = (const float*)d_in[2];
    const float* T         = (const float*)d_in[3];
    const float* q         = (const float*)d_in[4];
    const float* ps        = (const float*)d_in[5];
    const float* era5_lat  = (const float*)d_in[6];
    const float* era5_lon  = (const float*)d_in[7];
    const float* model_lat = (const float*)d_in[8];
    const float* model_lon = (const float*)d_in[9];
    const float* p_levels  = (const float*)d_in[10];
    const float* a_k       = (const float*)d_in[11];
    const float* b_k       = (const float*)d_in[12];

    float* wsf = (float*)d_ws;
    int*   ws_iy    = (int*)(wsf + WS_IY);
    float* ws_ty    = wsf + WS_TY;
    int*   ws_ix    = (int*)(wsf + WS_IX);
    float* ws_tx    = wsf + WS_TX;
    float* ws_logpe = wsf + WS_LOGPE;
    float* ws_psm   = wsf + WS_PSM;
    float* vars_h   = wsf + WS_VARSH;

    float* out = (float*)d_out;

    precompute_kernel<<<3, 256, 0, stream>>>(era5_lat, era5_lon, model_lat, model_lon,
                                             p_levels, ws_iy, ws_ty, ws_ix, ws_tx,
                                             ws_logpe);

    if (ws_size >= WS_NEEDED_FLOATS * sizeof(float)) {
        ps_kernel<<<(NPTS + 255) / 256, 256, 0, stream>>>(ps, ws_iy, ws_ty, ws_ix, ws_tx,
                                                          ws_psm, out);
        const int tot_h = NPTS * 5 * LL;
        horiz_kernel<<<(tot_h + 255) / 256, 256, 0, stream>>>(u, v, w, T, q,
                                                              ws_iy, ws_ty, ws_ix, ws_tx,
                                                              vars_h);
        const int tot_v = NPTS * KK;
        vert_kernel<<<(tot_v + 255) / 256, 256, 0, stream>>>(vars_h, ws_psm, p_levels,
                                                             ws_logpe, a_k, b_k, out);
    } else {
        main_kernel<<<(NPTS + 255) / 256, 256, 0, stream>>>(u, v, w, T, q, ps, p_levels,
                                                            a_k, b_k, ws_iy, ws_ty,
                                                            ws_ix, ws_tx, ws_logpe, out);
    }
}

// Round 3
// 230.983 us; speedup vs baseline: 1.2542x; 1.1195x over previous
//
#include <hip/hip_runtime.h>
#include <cmath>

#define HE 361
#define WE 720
#define LL 37
#define HM 180
#define WM 360
#define KK 32
#define NPTS (HM * WM)
#define EPSF 1e-8f
#define PTSB 8   // model points per block; 360 % 8 == 0 -> block never crosses a row

// out layout: out3d [HM*WM*KK*5] | p_model [HM*WM*KK] | ps_o [HM*WM]
#define OFF1 ((size_t)HM * WM * KK * 5)
#define OFF2 (OFF1 + (size_t)HM * WM * KK)

// ws layout (float units):
#define WS_IY    0
#define WS_TY    180
#define WS_IX    360
#define WS_TX    720
#define WS_LOGPE 1080

__device__ __forceinline__ int upper_bound_g(const float* a, int n, float v) {
    int lo = 0, hi = n;
    while (lo < hi) {
        int m = (lo + hi) >> 1;
        if (a[m] <= v) lo = m + 1; else hi = m;
    }
    return lo;  // searchsorted side='right'
}

__global__ void precompute_kernel(const float* __restrict__ era5_lat,
                                  const float* __restrict__ era5_lon,
                                  const float* __restrict__ model_lat,
                                  const float* __restrict__ model_lon,
                                  const float* __restrict__ p_levels,
                                  int* __restrict__ ws_iy, float* __restrict__ ws_ty,
                                  int* __restrict__ ws_ix, float* __restrict__ ws_tx,
                                  float* __restrict__ ws_logpe) {
    int t = blockIdx.x * blockDim.x + threadIdx.x;
    if (t < HM) {
        float v = model_lat[t];
        int i = upper_bound_g(era5_lat, HE, v) - 1;
        if (i < 0) i = 0;
        if (i > HE - 2) i = HE - 2;
        ws_iy[t] = i;
        ws_ty[t] = (v - era5_lat[i]) / (era5_lat[i + 1] - era5_lat[i]);
    } else if (t < HM + WM) {
        int j = t - HM;
        float v = model_lon[j];
        int i = upper_bound_g(era5_lon, WE, v) - 1;
        if (i < 0) i = 0;
        if (i > WE - 2) i = WE - 2;
        ws_ix[j] = i;
        ws_tx[j] = (v - era5_lon[i]) / (era5_lon[i + 1] - era5_lon[i]);
    } else if (t < HM + WM + LL) {
        int k = t - HM - WM;
        ws_logpe[k] = logf(p_levels[k] + EPSF);
    }
}

// Fused kernel: block of 256 threads handles PTSB=8 model points.
// Phase 1: horizontal bilinear for 8*185 channels -> LDS (24 loads in flight/thread).
// Phase 2: vertical log-p interpolation from LDS -> out (coalesced stores).
__global__ void __launch_bounds__(256)
fused_kernel(const float* __restrict__ u, const float* __restrict__ v,
             const float* __restrict__ w, const float* __restrict__ T,
             const float* __restrict__ q, const float* __restrict__ ps,
             const float* __restrict__ p_levels,
             const float* __restrict__ a_k, const float* __restrict__ b_k,
             const int* __restrict__ ws_iy, const float* __restrict__ ws_ty,
             const int* __restrict__ ws_ix, const float* __restrict__ ws_tx,
             const float* __restrict__ ws_logpe,
             float* __restrict__ out) {
    __shared__ float s_h[PTSB][5 * LL];   // 8 x 185; stride 185 % 32 = 25 -> conflict-free
    __shared__ float s_psm[PTSB];
    __shared__ float s_plev[LL];
    __shared__ float s_logpe[LL];
    __shared__ float s_ak[KK];
    __shared__ float s_bk[KK];

    const int tid = threadIdx.x;
    if (tid < LL) {
        s_plev[tid]  = p_levels[tid];
        s_logpe[tid] = ws_logpe[tid];
    } else if (tid >= 64 && tid < 64 + KK) {
        s_ak[tid - 64] = a_k[tid - 64];
        s_bk[tid - 64] = b_k[tid - 64];
    }

    const int pt_local = tid >> 5;          // 0..7
    const int grp      = tid & 31;          // 0..31
    const int pt = blockIdx.x * PTSB + pt_local;
    const int y  = pt / WM;
    const int x  = pt - y * WM;

    const int   iy = ws_iy[y];
    const float ty = ws_ty[y];
    const int   ix = ws_ix[x];
    const float tx = ws_tx[x];
    const float omty = 1.0f - ty;
    const float omtx = 1.0f - tx;

    const size_t b00 = (size_t)iy * WE + ix;

    if (grp == 0) {
        const float p00 = ps[b00], p01 = ps[b00 + 1];
        const float p10 = ps[b00 + WE], p11 = ps[b00 + WE + 1];
        const float ps_m = omty * (omtx * p00 + tx * p01) + ty * (omtx * p10 + tx * p11);
        s_psm[pt_local] = ps_m;
        out[OFF2 + pt] = fminf(fmaxf(ps_m, 30000.0f), 110000.0f);
    }

    const float* srcs0 = u;
    const float* srcs1 = v;
    const float* srcs2 = w;
    const float* srcs3 = T;
    const float* srcs4 = q;

#pragma unroll
    for (int it = 0; it < 6; it++) {
        const int ch = grp + 32 * it;
        if (ch < 5 * LL) {
            const int var = ch / LL;
            const int l   = ch - var * LL;
            const float* s = (var == 0) ? srcs0 : (var == 1) ? srcs1
                           : (var == 2) ? srcs2 : (var == 3) ? srcs3 : srcs4;
            const size_t c00 = b00 * LL + l;
            const float d00 = s[c00];
            const float d01 = s[c00 + LL];
            const float d10 = s[c00 + (size_t)WE * LL];
            const float d11 = s[c00 + (size_t)WE * LL + LL];
            s_h[pt_local][ch] = omty * (omtx * d00 + tx * d01) +
                                ty   * (omtx * d10 + tx * d11);
        }
    }

    __syncthreads();

    // Phase 2: thread = (pt_local, k)
    const int k = grp;
    const float ps_m = s_psm[pt_local];

    int nvalid = 0;
#pragma unroll
    for (int l = 0; l < LL; l++) nvalid += (s_plev[l] <= ps_m) ? 1 : 0;
    int maxi = nvalid - 2;
    if (maxi < 0) maxi = 0;

    const float pm = s_ak[k] + s_bk[k] * ps_m;
    out[OFF1 + (size_t)pt * KK + k] = pm;

    const float lpm = logf(pm + EPSF);
    int lo = 0, hi = LL;
    while (lo < hi) {
        int m = (lo + hi) >> 1;
        if (s_logpe[m] <= lpm) lo = m + 1; else hi = m;
    }
    int i = lo - 1;
    if (i < 0) i = 0;
    if (i > maxi) i = maxi;
    const float t = (lpm - s_logpe[i]) / (s_logpe[i + 1] - s_logpe[i]);

    const bool invalid = (nvalid < 2);
    const size_t obase = (size_t)pt * (KK * 5) + k * 5;
#pragma unroll
    for (int var = 0; var < 5; var++) {
        const float g0 = s_h[pt_local][var * LL + i];
        const float g1 = s_h[pt_local][var * LL + i + 1];
        float o = g0 + t * (g1 - g0);
        if (invalid) o = 0.0f;                       // zero BEFORE clip (matches ref)
        if (var == 3) o = fminf(fmaxf(o, 150.0f), 350.0f);
        if (var == 4) o = fminf(fmaxf(o, 0.0f), 0.05f);
        out[obase + var] = o;
    }
}

extern "C" void kernel_launch(void* const* d_in, const int* in_sizes, int n_in,
                              void* d_out, int out_size, void* d_ws, size_t ws_size,
                              hipStream_t stream) {
    const float* u         = (const float*)d_in[0];
    const float* v         = (const float*)d_in[1];
    const float* w         = (const float*)d_in[2];
    const float* T         = (const float*)d_in[3];
    const float* q         = (const float*)d_in[4];
    const float* ps        = (const float*)d_in[5];
    const float* era5_lat  = (const float*)d_in[6];
    const float* era5_lon  = (const float*)d_in[7];
    const float* model_lat = (const float*)d_in[8];
    const float* model_lon = (const float*)d_in[9];
    const float* p_levels  = (const float*)d_in[10];
    const float* a_k       = (const float*)d_in[11];
    const float* b_k       = (const float*)d_in[12];

    float* wsf = (float*)d_ws;
    int*   ws_iy    = (int*)(wsf + WS_IY);
    float* ws_ty    = wsf + WS_TY;
    int*   ws_ix    = (int*)(wsf + WS_IX);
    float* ws_tx    = wsf + WS_TX;
    float* ws_logpe = wsf + WS_LOGPE;

    float* out = (float*)d_out;

    precompute_kernel<<<3, 256, 0, stream>>>(era5_lat, era5_lon, model_lat, model_lon,
                                             p_levels, ws_iy, ws_ty, ws_ix, ws_tx,
                                             ws_logpe);

    const int blocks = NPTS / PTSB;   // 8100
    fused_kernel<<<blocks, 256, 0, stream>>>(u, v, w, T, q, ps, p_levels, a_k, b_k,
                                             ws_iy, ws_ty, ws_ix, ws_tx, ws_logpe, out);
}